// Round 15
// baseline (299.297 us; speedup 1.0000x reference)
//
#include <hip/hip_runtime.h>
#include <math.h>

// Min-sum BP LDPC decoder, LDS-resident messages, degree-sorted checks.
// One block = one batch element; padded msg arena (~160 KB) lives in LDS.
//
// R16 = R15 (297 total / 127.3 bp: stride ≡ 2 mod 4 + b64 checks + iter-0
// peel + xor-sign + exact-degree dispatch + big-fallback, zero spills) +
// WAVE-ALIGNED DEGREE BINS:
//  - R15 post-mortem: 2-var ILP batch neutral -> not read-latency-bound.
//    Remaining slack theory: waves straddling degree-bin boundaries in the
//    sorted check array execute MULTIPLE do_check_x<D> bodies under
//    complementary exec masks (~15 boundary waves / 64 wave-slots pay ~2x
//    -> ~1.2x check-phase issue).
//  - Fix: pad each degree bin start to a multiple of 64 with d=0 dummy
//    slots (no-op). Every wave is degree-uniform. NSLOT=5120 (5 slots per
//    thread). ws needs 2*NSLOT ints = 40960 B — empirically proven
//    available (R6's perm table required exactly 40960 and was written AND
//    applied). pad_stride(0)=0: dummies consume no arena.
//  - (pb,d,sb) packed into one pk[5] int (pb 16b | d<<16 | sb<<22):
//    net -3 registers vs R15's cstB[4]+dsb[4] (spill tripwire stays armed:
//    WRITE_SIZE must equal 16392 KB).
//  - Pure scheduling/layout: all FP arithmetic, operand orders, tie rule,
//    xor-sign identical to R15 -> bit-exact class unchanged.
//  - HARD CONSTRAINTS: 64-VGPR pin (R3/R9/R14); never reorder reference FP
//    math (R6); 2 dispatches (R7/R8/R13).

#define BLOCK 1024
#define NV    8192          // N variables
#define MC    4096          // M checks
#define NE    32768         // E edges (N * DV, DV=4)
#define VPT   (NV / BLOCK)  // 8 vars per thread
#define NSLOT 5120          // padded sorted-check slots (5 per thread)
#define CPS   (NSLOT / BLOCK)
#define NITER 10
#define ALPHA 0.8f
#define CLAMP 20.0f
#define MSGW  40896         // padded arena words (159.9 KB)
#define SGNB  0x80000000

// ws layout (ints), 40960 B (size proven available by R6's applied perm table):
//  [0 .. NSLOT)        : pbase(16b) | deg<<16   (wave-aligned degree bins)
//  [NSLOT .. 2*NSLOT)  : original check index (0 for dummy slots)

// stride: smallest s >= d with s ≡ 2 (mod 4); d==0 -> 0 (dummies are free)
__device__ __forceinline__ int pad_stride(int d) {
    return d ? (d + ((2 - (d & 3)) & 3)) : 0;
}

// ---------------- setup: counting-sort + wave-aligned bins + prefix --------
__global__ __launch_bounds__(BLOCK)
void setup_sort(const float* __restrict__ check_mask,
                const int*   __restrict__ check_adj,
                int max_dc, int* __restrict__ ws)
{
    __shared__ int hist[64], cursor[64], wsum[16];
    __shared__ int sdeg[NSLOT];
    const int t = threadIdx.x;
    if (t < 64) hist[t] = 0;
    for (int i = t; i < NSLOT; i += BLOCK) { sdeg[i] = 0; ws[NSLOT + i] = 0; }
    __syncthreads();
    int deg[4];
#pragma unroll
    for (int k = 0; k < 4; ++k) {
        const int c = t + k * BLOCK;
        int d = 0;
        for (int j = 0; j < max_dc; ++j)
            d += (check_mask[(size_t)c * max_dc + j] != 0.0f) ? 1 : 0;
        deg[k] = d;
        atomicAdd(&hist[d & 63], 1);
    }
    __syncthreads();
    // padded bin starts: round each bin start up to 64 while it still fits
    if (t == 0) {
        int s = 0, used = 0;
        for (int d = 0; d < 64; ++d) {
            cursor[d] = s;
            s    += hist[d];
            used += hist[d];
            const int ns = (s + 63) & ~63;
            if (ns + (MC - used) <= NSLOT) s = ns;   // graceful: skip pad if tight
        }
    }
    __syncthreads();
#pragma unroll
    for (int k = 0; k < 4; ++k) {
        const int pos = atomicAdd(&cursor[deg[k] & 63], 1);
        sdeg[pos]       = deg[k];
        ws[NSLOT + pos] = t + k * BLOCK;   // original check index
    }
    __syncthreads();
    // padded-base prefix over NSLOT slots; thread t owns 5t..5t+4
    int psz[CPS];
    int s = 0;
#pragma unroll
    for (int k = 0; k < CPS; ++k) {
        const int d = sdeg[CPS * t + k];
        psz[k] = s;
        s += pad_stride(d);
    }
    const int lane = t & 63, wv = t >> 6;
    int run = s;
#pragma unroll
    for (int off = 1; off < 64; off <<= 1) {
        const int n = __shfl_up(run, off, 64);
        if (lane >= off) run += n;
    }
    if (lane == 63) wsum[wv] = run;
    __syncthreads();
    if (t == 0) {
        int acc = 0;
        for (int w = 0; w < 16; ++w) { const int v = wsum[w]; wsum[w] = acc; acc += v; }
    }
    __syncthreads();
    const int tb = wsum[wv] + (run - s);
#pragma unroll
    for (int k = 0; k < CPS; ++k) {
        const int i = CPS * t + k;
        ws[i] = ((tb + psz[k]) & 0xFFFF) | (sdeg[i] << 16);
    }
}

// Exact-degree check update, b64 vectorized, byte-base addressing.
// ssb = syndrome sign bit (bit31). Bit-exact vs reference (validated R9-R15).
template<int D>
__device__ __forceinline__ void do_check_x(char* __restrict__ mb,
                                           int stB, int ssb, float pad)
{
    float x[D];
    constexpr int P = D / 2;
#pragma unroll
    for (int p = 0; p < P; ++p) {
        const float2 r = *(const float2*)(mb + stB + 8 * p);
        x[2 * p]     = r.x;
        x[2 * p + 1] = r.y;
    }
    if constexpr (D & 1)
        x[D - 1] = *(const float*)(mb + stB + 4 * (D - 1));

    float min1 = pad, min2 = pad;
    int sb = ssb;
#pragma unroll
    for (int j = 0; j < D; ++j) {
        sb ^= __float_as_int(x[j]);                     // sign parity (no -0.0)
        const float a = fabsf(x[j]);
        min2 = __builtin_amdgcn_fmed3f(min1, min2, a);  // uses OLD min1
        min1 = fminf(min1, a);
    }
    const float vm1 = ALPHA * min1;
    const float vm2 = ALPHA * min2;
#pragma unroll
    for (int p = 0; p < P; ++p) {
        const int j0 = 2 * p, j1 = 2 * p + 1;
        const float m0 = (fabsf(fabsf(x[j0]) - min1) < 1e-9f) ? vm2 : vm1;  // REF tie rule
        const float m1 = (fabsf(fabsf(x[j1]) - min1) < 1e-9f) ? vm2 : vm1;
        float2 w;
        w.x = __int_as_float(__float_as_int(m0) | ((sb ^ __float_as_int(x[j0])) & SGNB));
        w.y = __int_as_float(__float_as_int(m1) | ((sb ^ __float_as_int(x[j1])) & SGNB));
        *(float2*)(mb + stB + 8 * p) = w;
    }
    if constexpr (D & 1) {
        const int jt = D - 1;
        const float mt = (fabsf(fabsf(x[jt]) - min1) < 1e-9f) ? vm2 : vm1;
        *(float*)(mb + stB + 4 * jt) =
            __int_as_float(__float_as_int(mt) | ((sb ^ __float_as_int(x[jt])) & SGNB));
    }
}

// Generic fallback (LDS re-read): d<=3, 13+, and d==0 (dummy, no-op).
__device__ void do_check_big(char* __restrict__ mb,
                             int stB, int d, int ssb, float pad)
{
    float min1 = pad, min2 = pad;
    int sb = ssb;
    for (int j = 0; j < d; ++j) {
        const float xx = *(const float*)(mb + stB + 4 * j);
        sb ^= __float_as_int(xx);
        const float aa = fabsf(xx);
        min2 = __builtin_amdgcn_fmed3f(min1, min2, aa);
        min1 = fminf(min1, aa);
    }
    const float vm1 = ALPHA * min1;
    const float vm2 = ALPHA * min2;
    for (int j = 0; j < d; ++j) {
        const float xx = *(const float*)(mb + stB + 4 * j);
        const float m  = (fabsf(fabsf(xx) - min1) < 1e-9f) ? vm2 : vm1;
        *(float*)(mb + stB + 4 * j) =
            __int_as_float(__float_as_int(m) | ((sb ^ __float_as_int(xx)) & SGNB));
    }
}

// Check phase for one k-step: exact-degree tree (wave-uniform after padding).
__device__ __forceinline__ void check_dispatch(char* __restrict__ mb,
                                               int stB, int d, int ssb, float pad)
{
    if      (d == 8)  do_check_x<8>(mb, stB, ssb, pad);
    else if (d == 7)  do_check_x<7>(mb, stB, ssb, pad);
    else if (d == 9)  do_check_x<9>(mb, stB, ssb, pad);
    else if (d == 6)  do_check_x<6>(mb, stB, ssb, pad);
    else if (d == 10) do_check_x<10>(mb, stB, ssb, pad);
    else if (d == 5)  do_check_x<5>(mb, stB, ssb, pad);
    else if (d == 11) do_check_x<11>(mb, stB, ssb, pad);
    else if (d == 12) do_check_x<12>(mb, stB, ssb, pad);
    else if (d == 4)  do_check_x<4>(mb, stB, ssb, pad);
    else              do_check_big(mb, stB, d, ssb, pad);   // d<=3, 13.., 0
}

__global__ __launch_bounds__(BLOCK) __attribute__((amdgpu_waves_per_eu(4, 4)))
void bp_decode(const float* __restrict__ syndrome,    // (B, M)
               const float* __restrict__ llr_g,       // (B, N)
               const int*   __restrict__ var_adj,     // (N, 4)
               const int*   __restrict__ var_idx,     // (E,)
               const int*   __restrict__ check_adj,   // (M, max_dc)
               int max_dc,
               const int*   __restrict__ ws,          // wave-aligned sorted info
               float* __restrict__ out,               // marginals | hard | converged
               int B)
{
    __shared__ float msg[MSGW];  // padded arena, in-place ctv/vtc
    __shared__ float sh_e0;      // |vtc[edge 0]| snapshot for reference's pad
    __shared__ int   mism;

    const int b = blockIdx.x;
    const int t = threadIdx.x;
    char* mb = (char*)msg;

    // ---- load sorted-check info; build pos[e] in LDS (aliasing msg) ----
    int pk[CPS];   // pb(16b) | d<<16 | synbit<<22
    {
        int* posL = (int*)msg;
#pragma unroll
        for (int k = 0; k < CPS; ++k) {
            const int i = t + k * BLOCK;
            const int w = ws[i];
            const int c = ws[NSLOT + i];
            const int pb = w & 0xFFFF;
            const int d  = w >> 16;
            const int sb = (syndrome[(size_t)b * MC + c] > 0.5f) ? 1 : 0;
            pk[k] = pb | (d << 16) | (sb << 22);
            const int st = check_adj[(size_t)c * max_dc];  // first edge (contiguous)
            for (int j = 0; j < d; ++j)
                posL[st + j] = pb + j;
        }
    }
    __syncthreads();

    // ---- edge-0 owner info (reference's pad = |vtc[0]| + 1e6) ----
    const int  v0  = var_idx[0];
    const bool own = (t == (v0 & (BLOCK - 1)));      // thread that writes edge 0
    const int  e0B = ((const int*)msg)[0] << 2;      // posL[0] as byte offset

    // ---- var-side padded slots (byte offsets) + LLRs into registers ----
    int   vsB[VPT][4];
    float llr[VPT];
    {
        const int* posL = (const int*)msg;
#pragma unroll
        for (int k = 0; k < VPT; ++k) {
            const int v = t + k * BLOCK;
            const int4 a = ((const int4*)var_adj)[v];   // var degree is exactly 4
            vsB[k][0] = posL[a.x] << 2; vsB[k][1] = posL[a.y] << 2;
            vsB[k][2] = posL[a.z] << 2; vsB[k][3] = posL[a.w] << 2;
            llr[k] = llr_g[(size_t)b * NV + v];
        }
    }
    __syncthreads();   // posL reads done; msg may now be overwritten (no zero-fill:
                       // iter 0 writes every edge slot; pad gaps are never read)

    // ======== iter 0 (peeled): ctv==0 -> vtc = clip(llr), write-only ========
#pragma unroll
    for (int k = 0; k < VPT; ++k) {
        const float o = __builtin_amdgcn_fmed3f(llr[k], -CLAMP, CLAMP);
        *(float*)(mb + vsB[k][0]) = o;
        *(float*)(mb + vsB[k][1]) = o;
        *(float*)(mb + vsB[k][2]) = o;
        *(float*)(mb + vsB[k][3]) = o;
    }
    if (own) sh_e0 = fabsf(*(const float*)(mb + e0B)) + 1.0e6f;  // own write, RAW-ordered
    __syncthreads();
    {
        const float pad = sh_e0;
#pragma unroll
        for (int k = 0; k < CPS; ++k)
            check_dispatch(mb, (pk[k] & 0xFFFF) << 2, (pk[k] >> 16) & 63,
                           ((pk[k] >> 22) & 1) << 31, pad);
    }
    __syncthreads();

    // ======== iters 1..NITER-1 ========
#pragma unroll 1
    for (int it = 1; it < NITER; ++it) {
        // ---- variable phase, 2-var batches (R15; values identical) ----
#pragma unroll
        for (int k = 0; k < VPT; k += 2) {
            const float a0 = *(const float*)(mb + vsB[k][0]);
            const float a1 = *(const float*)(mb + vsB[k][1]);
            const float a2 = *(const float*)(mb + vsB[k][2]);
            const float a3 = *(const float*)(mb + vsB[k][3]);
            const float b0 = *(const float*)(mb + vsB[k + 1][0]);
            const float b1 = *(const float*)(mb + vsB[k + 1][1]);
            const float b2 = *(const float*)(mb + vsB[k + 1][2]);
            const float b3 = *(const float*)(mb + vsB[k + 1][3]);

            const float totA = ((a0 + a1) + a2) + a3;   // reference sum order
            const float bseA = llr[k] + totA;
            *(float*)(mb + vsB[k][0]) = __builtin_amdgcn_fmed3f(bseA - a0, -CLAMP, CLAMP);
            *(float*)(mb + vsB[k][1]) = __builtin_amdgcn_fmed3f(bseA - a1, -CLAMP, CLAMP);
            *(float*)(mb + vsB[k][2]) = __builtin_amdgcn_fmed3f(bseA - a2, -CLAMP, CLAMP);
            *(float*)(mb + vsB[k][3]) = __builtin_amdgcn_fmed3f(bseA - a3, -CLAMP, CLAMP);

            const float totB = ((b0 + b1) + b2) + b3;
            const float bseB = llr[k + 1] + totB;
            *(float*)(mb + vsB[k + 1][0]) = __builtin_amdgcn_fmed3f(bseB - b0, -CLAMP, CLAMP);
            *(float*)(mb + vsB[k + 1][1]) = __builtin_amdgcn_fmed3f(bseB - b1, -CLAMP, CLAMP);
            *(float*)(mb + vsB[k + 1][2]) = __builtin_amdgcn_fmed3f(bseB - b2, -CLAMP, CLAMP);
            *(float*)(mb + vsB[k + 1][3]) = __builtin_amdgcn_fmed3f(bseB - b3, -CLAMP, CLAMP);
        }
        if (own) sh_e0 = fabsf(*(const float*)(mb + e0B)) + 1.0e6f;   // own write, ordered
        __syncthreads();
        const float pad = sh_e0;

        // ---- check phase: wave-uniform degree bins, b64 pairs ----
#pragma unroll
        for (int k = 0; k < CPS; ++k)
            check_dispatch(mb, (pk[k] & 0xFFFF) << 2, (pk[k] >> 16) & 63,
                           ((pk[k] >> 22) & 1) << 31, pad);
        __syncthreads();
    }

    // ---- finale: marginals, hard decisions, convergence ----
    float marg[VPT], hard[VPT];
#pragma unroll
    for (int k = 0; k < VPT; ++k) {
        const float c0 = *(const float*)(mb + vsB[k][0]);
        const float c1 = *(const float*)(mb + vsB[k][1]);
        const float c2 = *(const float*)(mb + vsB[k][2]);
        const float c3 = *(const float*)(mb + vsB[k][3]);
        const float tot = ((c0 + c1) + c2) + c3;
        const float tl  = llr[k] + tot;
        const float mg  = 1.0f / (1.0f + expf(tl));   // sigmoid(-tl)
        marg[k] = mg;
        hard[k] = (mg > 0.5f) ? 1.0f : 0.0f;
    }
    if (t == 0) mism = 0;
    __syncthreads();   // all ctv reads done; safe to overwrite msg

    const size_t BN = (size_t)B * NV;
#pragma unroll
    for (int k = 0; k < VPT; ++k) {
        const int v = t + k * BLOCK;
        out[(size_t)b * NV + v]      = marg[k];        // output 0: marginals
        out[BN + (size_t)b * NV + v] = hard[k];        // output 1: hard_decision
        const float h = hard[k];                       // scatter hard bit to edges
        *(float*)(mb + vsB[k][0]) = h;
        *(float*)(mb + vsB[k][1]) = h;
        *(float*)(mb + vsB[k][2]) = h;
        *(float*)(mb + vsB[k][3]) = h;
    }
    __syncthreads();

    // syn_hat[c] = parity over the check's edges' hard bits; converged iff == syndrome
#pragma unroll
    for (int k = 0; k < CPS; ++k) {
        const int d   = (pk[k] >> 16) & 63;
        const int sb  = (pk[k] >> 22) & 1;
        const int stB = (pk[k] & 0xFFFF) << 2;
        int par = 0;
        for (int j = 0; j < d; ++j)
            par ^= (*(const float*)(mb + stB + 4 * j) != 0.0f) ? 1 : 0;
        if ((par != sb) && d) mism = 1;   // dummies (d==0) never vote
    }
    __syncthreads();
    if (t == 0) out[2 * BN + b] = mism ? 0.0f : 1.0f;  // output 2: converged
}

extern "C" void kernel_launch(void* const* d_in, const int* in_sizes, int n_in,
                              void* d_out, int out_size, void* d_ws, size_t ws_size,
                              hipStream_t stream) {
    const float* syndrome   = (const float*)d_in[0];
    const float* llr        = (const float*)d_in[1];
    const int*   var_adj    = (const int*)d_in[2];
    // d_in[3] var_adj_mask: all ones (DV=4 exact) — unused
    const int*   check_adj  = (const int*)d_in[4];
    const float* check_mask = (const float*)d_in[5];
    const int*   var_idx    = (const int*)d_in[6];
    // d_in[7] pcm_dense — unused
    float* out = (float*)d_out;
    int*   ws  = (int*)d_ws;    // needs 2*NSLOT ints = 40960 B (proven: R6)

    const int B      = in_sizes[0] / MC;      // 256
    const int max_dc = in_sizes[4] / MC;

    setup_sort<<<1, BLOCK, 0, stream>>>(check_mask, check_adj, max_dc, ws);
    bp_decode<<<B, BLOCK, 0, stream>>>(syndrome, llr, var_adj, var_idx,
                                       check_adj, max_dc, ws, out, B);
}

// Round 16
// 299.065 us; speedup vs baseline: 1.0008x; 1.0008x over previous
//
#include <hip/hip_runtime.h>
#include <math.h>

// Min-sum BP LDPC decoder, LDS-resident messages, degree-sorted checks.
// One block = one batch element; padded msg arena (~160 KB) lives in LDS.
//
// R17 = R16's bp_decode, BYTE-IDENTICAL (107.8 us: stride ≡ 2 mod 4 + b64
// checks + iter-0 peel + xor-sign + exact-degree dispatch + WAVE-ALIGNED
// degree bins, zero spills) + SCAN-FREE SETUP:
//  - R16 post-mortem: wave-aligned bins -15%; decode now ~LDS-pipe-bound
//    (171k of 259k cyc: 110k base + 61k var-gather conflicts). All bit-exact
//    conflict attacks are proven-null or VALU-negative -> decode FROZEN.
//  - Setup's 96 uncoalesced scalar mask loads/check replaced by 2 loads:
//    edges are sorted by check (np.nonzero row-major), so st_c =
//    check_adj[c][0] is strictly increasing over non-empty checks and
//    d_c = suffixmin_{c'>c}(st) - st_c. Empty checks (P ~ 3.4e-4) flagged
//    by mask[c][0] (mask rows fill from j=0). 13-step Hillis-Steele
//    suffix-min in LDS. Setup GPU ~12 -> ~3 us.
//  - ws format + decode untouched; bp counters must be identical
//    (conflicts ~1.7e7, VGPR 64, WRITE 16392 KB) else bug.
//  - HARD CONSTRAINTS: 64-VGPR pin (R3/R9/R14); never reorder reference FP
//    math (R6); 2 dispatches (R7/R8/R13).

#define BLOCK 1024
#define NV    8192          // N variables
#define MC    4096          // M checks
#define NE    32768         // E edges (N * DV, DV=4)
#define VPT   (NV / BLOCK)  // 8 vars per thread
#define NSLOT 5120          // padded sorted-check slots (5 per thread)
#define CPS   (NSLOT / BLOCK)
#define NITER 10
#define ALPHA 0.8f
#define CLAMP 20.0f
#define MSGW  40896         // padded arena words (159.9 KB)
#define SGNB  0x80000000

// ws layout (ints), 40960 B (size proven available by R6's applied perm table):
//  [0 .. NSLOT)        : pbase(16b) | deg<<16   (wave-aligned degree bins)
//  [NSLOT .. 2*NSLOT)  : original check index (0 for dummy slots)

// stride: smallest s >= d with s ≡ 2 (mod 4); d==0 -> 0 (dummies are free)
__device__ __forceinline__ int pad_stride(int d) {
    return d ? (d + ((2 - (d & 3)) & 3)) : 0;
}

// ---------------- setup: scan-free degrees + wave-aligned bins --------------
__global__ __launch_bounds__(BLOCK)
void setup_sort(const float* __restrict__ check_mask,
                const int*   __restrict__ check_adj,
                int max_dc, int* __restrict__ ws)
{
    __shared__ int sfx[MC + 1];          // st (or NE sentinel) -> suffix min
    __shared__ int hist[64], cursor[64], wsum[16];
    __shared__ int sdeg[NSLOT];
    const int t = threadIdx.x;
    if (t < 64) hist[t] = 0;
    for (int i = t; i < NSLOT; i += BLOCK) { sdeg[i] = 0; ws[NSLOT + i] = 0; }

    // ---- 2 loads per check: nonempty flag + row start ----
    int stv[4], nz[4];
#pragma unroll
    for (int k = 0; k < 4; ++k) {
        const int c = t + k * BLOCK;
        nz[k]  = (check_mask[(size_t)c * max_dc] != 0.0f) ? 1 : 0;  // d>=1 iff [c][0] set
        stv[k] = check_adj[(size_t)c * max_dc];                     // first edge
        sfx[c] = nz[k] ? stv[k] : NE;
    }
    if (t == 0) sfx[MC] = NE;
    __syncthreads();

    // ---- Hillis-Steele suffix-min over MC+1 entries (13 steps) ----
    for (int off = 1; off <= MC; off <<= 1) {
        int v[4];
#pragma unroll
        for (int k = 0; k < 4; ++k) {
            const int c = t + k * BLOCK;
            const int o = c + off;
            const int a = sfx[c];
            v[k] = (o <= MC) ? min(a, sfx[o]) : a;
        }
        __syncthreads();
#pragma unroll
        for (int k = 0; k < 4; ++k) sfx[t + k * BLOCK] = v[k];
        __syncthreads();
    }

    // ---- degrees: d = suffixmin(st, c'>c) - st_c  (0 for empty checks) ----
    int deg[4];
#pragma unroll
    for (int k = 0; k < 4; ++k) {
        const int c = t + k * BLOCK;
        deg[k] = nz[k] ? (sfx[c + 1] - stv[k]) : 0;
        atomicAdd(&hist[deg[k] & 63], 1);
    }
    __syncthreads();

    // ---- padded bin starts: round each bin up to 64 while it fits ----
    if (t == 0) {
        int s = 0, used = 0;
        for (int d = 0; d < 64; ++d) {
            cursor[d] = s;
            s    += hist[d];
            used += hist[d];
            const int ns = (s + 63) & ~63;
            if (ns + (MC - used) <= NSLOT) s = ns;   // graceful: skip pad if tight
        }
    }
    __syncthreads();
#pragma unroll
    for (int k = 0; k < 4; ++k) {
        const int pos = atomicAdd(&cursor[deg[k] & 63], 1);
        sdeg[pos]       = deg[k];
        ws[NSLOT + pos] = t + k * BLOCK;   // original check index
    }
    __syncthreads();

    // ---- padded-base prefix over NSLOT slots; thread t owns 5t..5t+4 ----
    int psz[CPS];
    int s = 0;
#pragma unroll
    for (int k = 0; k < CPS; ++k) {
        const int d = sdeg[CPS * t + k];
        psz[k] = s;
        s += pad_stride(d);
    }
    const int lane = t & 63, wv = t >> 6;
    int run = s;
#pragma unroll
    for (int off = 1; off < 64; off <<= 1) {
        const int n = __shfl_up(run, off, 64);
        if (lane >= off) run += n;
    }
    if (lane == 63) wsum[wv] = run;
    __syncthreads();
    if (t == 0) {
        int acc = 0;
        for (int w = 0; w < 16; ++w) { const int v = wsum[w]; wsum[w] = acc; acc += v; }
    }
    __syncthreads();
    const int tb = wsum[wv] + (run - s);
#pragma unroll
    for (int k = 0; k < CPS; ++k) {
        const int i = CPS * t + k;
        ws[i] = ((tb + psz[k]) & 0xFFFF) | (sdeg[i] << 16);
    }
}

// Exact-degree check update, b64 vectorized, byte-base addressing.
// ssb = syndrome sign bit (bit31). Bit-exact vs reference (validated R9-R16).
template<int D>
__device__ __forceinline__ void do_check_x(char* __restrict__ mb,
                                           int stB, int ssb, float pad)
{
    float x[D];
    constexpr int P = D / 2;
#pragma unroll
    for (int p = 0; p < P; ++p) {
        const float2 r = *(const float2*)(mb + stB + 8 * p);
        x[2 * p]     = r.x;
        x[2 * p + 1] = r.y;
    }
    if constexpr (D & 1)
        x[D - 1] = *(const float*)(mb + stB + 4 * (D - 1));

    float min1 = pad, min2 = pad;
    int sb = ssb;
#pragma unroll
    for (int j = 0; j < D; ++j) {
        sb ^= __float_as_int(x[j]);                     // sign parity (no -0.0)
        const float a = fabsf(x[j]);
        min2 = __builtin_amdgcn_fmed3f(min1, min2, a);  // uses OLD min1
        min1 = fminf(min1, a);
    }
    const float vm1 = ALPHA * min1;
    const float vm2 = ALPHA * min2;
#pragma unroll
    for (int p = 0; p < P; ++p) {
        const int j0 = 2 * p, j1 = 2 * p + 1;
        const float m0 = (fabsf(fabsf(x[j0]) - min1) < 1e-9f) ? vm2 : vm1;  // REF tie rule
        const float m1 = (fabsf(fabsf(x[j1]) - min1) < 1e-9f) ? vm2 : vm1;
        float2 w;
        w.x = __int_as_float(__float_as_int(m0) | ((sb ^ __float_as_int(x[j0])) & SGNB));
        w.y = __int_as_float(__float_as_int(m1) | ((sb ^ __float_as_int(x[j1])) & SGNB));
        *(float2*)(mb + stB + 8 * p) = w;
    }
    if constexpr (D & 1) {
        const int jt = D - 1;
        const float mt = (fabsf(fabsf(x[jt]) - min1) < 1e-9f) ? vm2 : vm1;
        *(float*)(mb + stB + 4 * jt) =
            __int_as_float(__float_as_int(mt) | ((sb ^ __float_as_int(x[jt])) & SGNB));
    }
}

// Generic fallback (LDS re-read): d<=3, 13+, and d==0 (dummy, no-op).
__device__ void do_check_big(char* __restrict__ mb,
                             int stB, int d, int ssb, float pad)
{
    float min1 = pad, min2 = pad;
    int sb = ssb;
    for (int j = 0; j < d; ++j) {
        const float xx = *(const float*)(mb + stB + 4 * j);
        sb ^= __float_as_int(xx);
        const float aa = fabsf(xx);
        min2 = __builtin_amdgcn_fmed3f(min1, min2, aa);
        min1 = fminf(min1, aa);
    }
    const float vm1 = ALPHA * min1;
    const float vm2 = ALPHA * min2;
    for (int j = 0; j < d; ++j) {
        const float xx = *(const float*)(mb + stB + 4 * j);
        const float m  = (fabsf(fabsf(xx) - min1) < 1e-9f) ? vm2 : vm1;
        *(float*)(mb + stB + 4 * j) =
            __int_as_float(__float_as_int(m) | ((sb ^ __float_as_int(xx)) & SGNB));
    }
}

// Check phase for one k-step: exact-degree tree (wave-uniform after padding).
__device__ __forceinline__ void check_dispatch(char* __restrict__ mb,
                                               int stB, int d, int ssb, float pad)
{
    if      (d == 8)  do_check_x<8>(mb, stB, ssb, pad);
    else if (d == 7)  do_check_x<7>(mb, stB, ssb, pad);
    else if (d == 9)  do_check_x<9>(mb, stB, ssb, pad);
    else if (d == 6)  do_check_x<6>(mb, stB, ssb, pad);
    else if (d == 10) do_check_x<10>(mb, stB, ssb, pad);
    else if (d == 5)  do_check_x<5>(mb, stB, ssb, pad);
    else if (d == 11) do_check_x<11>(mb, stB, ssb, pad);
    else if (d == 12) do_check_x<12>(mb, stB, ssb, pad);
    else if (d == 4)  do_check_x<4>(mb, stB, ssb, pad);
    else              do_check_big(mb, stB, d, ssb, pad);   // d<=3, 13.., 0
}

__global__ __launch_bounds__(BLOCK) __attribute__((amdgpu_waves_per_eu(4, 4)))
void bp_decode(const float* __restrict__ syndrome,    // (B, M)
               const float* __restrict__ llr_g,       // (B, N)
               const int*   __restrict__ var_adj,     // (N, 4)
               const int*   __restrict__ var_idx,     // (E,)
               const int*   __restrict__ check_adj,   // (M, max_dc)
               int max_dc,
               const int*   __restrict__ ws,          // wave-aligned sorted info
               float* __restrict__ out,               // marginals | hard | converged
               int B)
{
    __shared__ float msg[MSGW];  // padded arena, in-place ctv/vtc
    __shared__ float sh_e0;      // |vtc[edge 0]| snapshot for reference's pad
    __shared__ int   mism;

    const int b = blockIdx.x;
    const int t = threadIdx.x;
    char* mb = (char*)msg;

    // ---- load sorted-check info; build pos[e] in LDS (aliasing msg) ----
    int pk[CPS];   // pb(16b) | d<<16 | synbit<<22
    {
        int* posL = (int*)msg;
#pragma unroll
        for (int k = 0; k < CPS; ++k) {
            const int i = t + k * BLOCK;
            const int w = ws[i];
            const int c = ws[NSLOT + i];
            const int pb = w & 0xFFFF;
            const int d  = w >> 16;
            const int sb = (syndrome[(size_t)b * MC + c] > 0.5f) ? 1 : 0;
            pk[k] = pb | (d << 16) | (sb << 22);
            const int st = check_adj[(size_t)c * max_dc];  // first edge (contiguous)
            for (int j = 0; j < d; ++j)
                posL[st + j] = pb + j;
        }
    }
    __syncthreads();

    // ---- edge-0 owner info (reference's pad = |vtc[0]| + 1e6) ----
    const int  v0  = var_idx[0];
    const bool own = (t == (v0 & (BLOCK - 1)));      // thread that writes edge 0
    const int  e0B = ((const int*)msg)[0] << 2;      // posL[0] as byte offset

    // ---- var-side padded slots (byte offsets) + LLRs into registers ----
    int   vsB[VPT][4];
    float llr[VPT];
    {
        const int* posL = (const int*)msg;
#pragma unroll
        for (int k = 0; k < VPT; ++k) {
            const int v = t + k * BLOCK;
            const int4 a = ((const int4*)var_adj)[v];   // var degree is exactly 4
            vsB[k][0] = posL[a.x] << 2; vsB[k][1] = posL[a.y] << 2;
            vsB[k][2] = posL[a.z] << 2; vsB[k][3] = posL[a.w] << 2;
            llr[k] = llr_g[(size_t)b * NV + v];
        }
    }
    __syncthreads();   // posL reads done; msg may now be overwritten (no zero-fill:
                       // iter 0 writes every edge slot; pad gaps are never read)

    // ======== iter 0 (peeled): ctv==0 -> vtc = clip(llr), write-only ========
#pragma unroll
    for (int k = 0; k < VPT; ++k) {
        const float o = __builtin_amdgcn_fmed3f(llr[k], -CLAMP, CLAMP);
        *(float*)(mb + vsB[k][0]) = o;
        *(float*)(mb + vsB[k][1]) = o;
        *(float*)(mb + vsB[k][2]) = o;
        *(float*)(mb + vsB[k][3]) = o;
    }
    if (own) sh_e0 = fabsf(*(const float*)(mb + e0B)) + 1.0e6f;  // own write, RAW-ordered
    __syncthreads();
    {
        const float pad = sh_e0;
#pragma unroll
        for (int k = 0; k < CPS; ++k)
            check_dispatch(mb, (pk[k] & 0xFFFF) << 2, (pk[k] >> 16) & 63,
                           ((pk[k] >> 22) & 1) << 31, pad);
    }
    __syncthreads();

    // ======== iters 1..NITER-1 ========
#pragma unroll 1
    for (int it = 1; it < NITER; ++it) {
        // ---- variable phase, 2-var batches (R15; values identical) ----
#pragma unroll
        for (int k = 0; k < VPT; k += 2) {
            const float a0 = *(const float*)(mb + vsB[k][0]);
            const float a1 = *(const float*)(mb + vsB[k][1]);
            const float a2 = *(const float*)(mb + vsB[k][2]);
            const float a3 = *(const float*)(mb + vsB[k][3]);
            const float b0 = *(const float*)(mb + vsB[k + 1][0]);
            const float b1 = *(const float*)(mb + vsB[k + 1][1]);
            const float b2 = *(const float*)(mb + vsB[k + 1][2]);
            const float b3 = *(const float*)(mb + vsB[k + 1][3]);

            const float totA = ((a0 + a1) + a2) + a3;   // reference sum order
            const float bseA = llr[k] + totA;
            *(float*)(mb + vsB[k][0]) = __builtin_amdgcn_fmed3f(bseA - a0, -CLAMP, CLAMP);
            *(float*)(mb + vsB[k][1]) = __builtin_amdgcn_fmed3f(bseA - a1, -CLAMP, CLAMP);
            *(float*)(mb + vsB[k][2]) = __builtin_amdgcn_fmed3f(bseA - a2, -CLAMP, CLAMP);
            *(float*)(mb + vsB[k][3]) = __builtin_amdgcn_fmed3f(bseA - a3, -CLAMP, CLAMP);

            const float totB = ((b0 + b1) + b2) + b3;
            const float bseB = llr[k + 1] + totB;
            *(float*)(mb + vsB[k + 1][0]) = __builtin_amdgcn_fmed3f(bseB - b0, -CLAMP, CLAMP);
            *(float*)(mb + vsB[k + 1][1]) = __builtin_amdgcn_fmed3f(bseB - b1, -CLAMP, CLAMP);
            *(float*)(mb + vsB[k + 1][2]) = __builtin_amdgcn_fmed3f(bseB - b2, -CLAMP, CLAMP);
            *(float*)(mb + vsB[k + 1][3]) = __builtin_amdgcn_fmed3f(bseB - b3, -CLAMP, CLAMP);
        }
        if (own) sh_e0 = fabsf(*(const float*)(mb + e0B)) + 1.0e6f;   // own write, ordered
        __syncthreads();
        const float pad = sh_e0;

        // ---- check phase: wave-uniform degree bins, b64 pairs ----
#pragma unroll
        for (int k = 0; k < CPS; ++k)
            check_dispatch(mb, (pk[k] & 0xFFFF) << 2, (pk[k] >> 16) & 63,
                           ((pk[k] >> 22) & 1) << 31, pad);
        __syncthreads();
    }

    // ---- finale: marginals, hard decisions, convergence ----
    float marg[VPT], hard[VPT];
#pragma unroll
    for (int k = 0; k < VPT; ++k) {
        const float c0 = *(const float*)(mb + vsB[k][0]);
        const float c1 = *(const float*)(mb + vsB[k][1]);
        const float c2 = *(const float*)(mb + vsB[k][2]);
        const float c3 = *(const float*)(mb + vsB[k][3]);
        const float tot = ((c0 + c1) + c2) + c3;
        const float tl  = llr[k] + tot;
        const float mg  = 1.0f / (1.0f + expf(tl));   // sigmoid(-tl)
        marg[k] = mg;
        hard[k] = (mg > 0.5f) ? 1.0f : 0.0f;
    }
    if (t == 0) mism = 0;
    __syncthreads();   // all ctv reads done; safe to overwrite msg

    const size_t BN = (size_t)B * NV;
#pragma unroll
    for (int k = 0; k < VPT; ++k) {
        const int v = t + k * BLOCK;
        out[(size_t)b * NV + v]      = marg[k];        // output 0: marginals
        out[BN + (size_t)b * NV + v] = hard[k];        // output 1: hard_decision
        const float h = hard[k];                       // scatter hard bit to edges
        *(float*)(mb + vsB[k][0]) = h;
        *(float*)(mb + vsB[k][1]) = h;
        *(float*)(mb + vsB[k][2]) = h;
        *(float*)(mb + vsB[k][3]) = h;
    }
    __syncthreads();

    // syn_hat[c] = parity over the check's edges' hard bits; converged iff == syndrome
#pragma unroll
    for (int k = 0; k < CPS; ++k) {
        const int d   = (pk[k] >> 16) & 63;
        const int sb  = (pk[k] >> 22) & 1;
        const int stB = (pk[k] & 0xFFFF) << 2;
        int par = 0;
        for (int j = 0; j < d; ++j)
            par ^= (*(const float*)(mb + stB + 4 * j) != 0.0f) ? 1 : 0;
        if ((par != sb) && d) mism = 1;   // dummies (d==0) never vote
    }
    __syncthreads();
    if (t == 0) out[2 * BN + b] = mism ? 0.0f : 1.0f;  // output 2: converged
}

extern "C" void kernel_launch(void* const* d_in, const int* in_sizes, int n_in,
                              void* d_out, int out_size, void* d_ws, size_t ws_size,
                              hipStream_t stream) {
    const float* syndrome   = (const float*)d_in[0];
    const float* llr        = (const float*)d_in[1];
    const int*   var_adj    = (const int*)d_in[2];
    // d_in[3] var_adj_mask: all ones (DV=4 exact) — unused
    const int*   check_adj  = (const int*)d_in[4];
    const float* check_mask = (const float*)d_in[5];
    const int*   var_idx    = (const int*)d_in[6];
    // d_in[7] pcm_dense — unused
    float* out = (float*)d_out;
    int*   ws  = (int*)d_ws;    // needs 2*NSLOT ints = 40960 B (proven: R6)

    const int B      = in_sizes[0] / MC;      // 256
    const int max_dc = in_sizes[4] / MC;

    setup_sort<<<1, BLOCK, 0, stream>>>(check_mask, check_adj, max_dc, ws);
    bp_decode<<<B, BLOCK, 0, stream>>>(syndrome, llr, var_adj, var_idx,
                                       check_adj, max_dc, ws, out, B);
}